// Round 4
// baseline (277.394 us; speedup 1.0000x reference)
//
#include <hip/hip_runtime.h>
#include <math.h>

#define W_IN     16384
#define FLT      32
#define W_OUT    (W_IN - FLT + 1)      // 16353
#define NT       256
#define GRP      256                   // outputs per MFMA group
#define GPW      4                     // consecutive groups per wave
#define NGRP     64                    // groups per row (64*256 = 16384 >= 16353)
#define LUT_N    2048
#define LUT_MAXM 16.0f                 // inputs are N(0,1); max mag ~6.2 << 16
#define LUT_SCL  (LUT_N / LUT_MAXM)    // 128.0f
#define OUT_SCALE 0.17782794100389228f // sqrt(10^(-15/10)); folded into taps
#define PMAX     (W_IN - 8)            // last in-bounds 8-float chunk start

typedef short  short8 __attribute__((ext_vector_type(8)));   // 8 bf16 = 4 VGPR
typedef float  f32x4  __attribute__((ext_vector_type(4)));   // MFMA acc

// Truncate-split f32 -> bf16 hi + bf16 lo. x == hi + lo + O(2^-17 * x).
__device__ __forceinline__ void bsplit(float x, unsigned short& h, unsigned short& l) {
    const unsigned u = __float_as_uint(x);
    h = (unsigned short)(u >> 16);
    const float rem = x - __uint_as_float(u & 0xffff0000u);  // exact
    l = (unsigned short)(__float_as_uint(rem) >> 16);
}

// ---- pre-kernel: pair LUT  lut2[k] = (g(k), g(k+1)-g(k)),  g = h(m)/m ----
__device__ __forceinline__ float gfun(const float* c1, const float* c2, int k) {
    if (k == 0) {
        float g0 = 0.f;
#pragma unroll
        for (int j = 0; j < 8; ++j) g0 += c2[j] * c1[j];   // lim h(m)/m
        return g0;
    }
    const float m = (float)k * (LUT_MAXM / LUT_N);
    float h = 0.f;
#pragma unroll
    for (int j = 0; j < 8; ++j) h += c2[j] * tanhf(c1[j] * m);
    return h / m;
}

__global__ void build_lut_kernel(const float* __restrict__ w1,
                                 const float* __restrict__ w2,
                                 float2* __restrict__ lut2) {
    const int k = blockIdx.x * blockDim.x + threadIdx.x;
    if (k >= LUT_N) return;
    float c1[8], c2[8];
#pragma unroll
    for (int j = 0; j < 8; ++j) { c1[j] = w1[j]; c2[j] = w2[j]; }
    const float g0 = gfun(c1, c2, k);
    const float g1 = gfun(c1, c2, k + 1);
    lut2[k] = make_float2(g0, g1 - g0);   // interp = fma(frac, d, g)
}

#define MFMA(a, b, c) __builtin_amdgcn_mfma_f32_16x16x32_bf16((a), (b), (c), 0, 0, 0)

// env+MLP for 8 contiguous elements held in registers -> 4 bf16 short8 frags.
__device__ __forceinline__ void env8(const float2* __restrict__ slut,
                                     float4 r0, float4 r1, float4 i0, float4 i1,
                                     short8& xh, short8& xl, short8& yh, short8& yl) {
    const float ar[8] = {r0.x, r0.y, r0.z, r0.w, r1.x, r1.y, r1.z, r1.w};
    const float ai[8] = {i0.x, i0.y, i0.z, i0.w, i1.x, i1.y, i1.z, i1.w};
#pragma unroll
    for (int e = 0; e < 8; ++e) {
        const float a = ar[e], b = ai[e];
        const float s = fmaxf(fmaf(a, a, b * b), 1e-30f);
        const float rs = rsqrtf(s);
        const float mag  = s * rs;               // sqrt(s), fast
        const float idxf = mag * LUT_SCL;
        int i = (int)idxf;
        i = min(i, LUT_N - 1);
        const float fr = idxf - (float)i;
        const float2 gd = slut[i];               // one ds_read_b64
        const float gg = fmaf(fr, gd.y, gd.x);   // h(mag)/mag
        unsigned short h, l;
        bsplit(a * gg, h, l); xh[e] = (short)h; xl[e] = (short)l;
        bsplit(b * gg, h, l); yh[e] = (short)h; yl[e] = (short)l;
    }
}

// Wave-independent FIR-as-MFMA: no x' staging in LDS, no inter-phase barriers.
// Each lane loads + envelopes exactly the 16 elements its B-fragment needs
// (~3.8x redundant VALU, coalesced loads); waves pipeline 4 groups each.
__global__ __launch_bounds__(NT, 4)
void fused_env_mlp_fir_kernel(const float* __restrict__ xr,
                              const float* __restrict__ xi,
                              const float2* __restrict__ lut2,
                              const float* __restrict__ wlr,  // [32]
                              const float* __restrict__ wli,  // [32]
                              float* __restrict__ out)        // [1024, 16353, 2]
{
    __shared__ float2 slut[LUT_N];     // 16 KB: (g, dg) pairs

    const int tid  = threadIdx.x;
    const int lane = tid & 63;
    const int rr   = lane & 15;        // output col block / B-frag n
    const int jj   = lane >> 4;        // k-subgroup

    // ---- LUT -> LDS (the only barrier in the kernel) ----
    for (int i = tid; i < LUT_N / 2; i += NT)
        ((float4*)slut)[i] = ((const float4*)lut2)[i];

    // ---- Banded-Toeplitz filter A-fragments (regs; scale folded in) ----
    // A_c[m][k] = f[k - m + 32c], m = lane&15, k = 8*(lane>>4)+e.
    short8 frh[2], frl[2], fih[2], fil[2];
    {
#pragma unroll
        for (int c = 0; c < 2; ++c) {
#pragma unroll
            for (int e = 0; e < 8; ++e) {
                const int t = 8 * jj + e - rr + 32 * c;
                const bool v = ((unsigned)t < 32u);
                const int ti = v ? t : 0;
                const float fr_ = v ? wlr[ti] * OUT_SCALE : 0.f;
                const float fi_ = v ? wli[ti] * OUT_SCALE : 0.f;
                unsigned short h, l;
                bsplit(fr_, h, l); frh[c][e] = (short)h; frl[c][e] = (short)l;
                bsplit(fi_, h, l); fih[c][e] = (short)h; fil[c][e] = (short)l;
            }
        }
    }
    __syncthreads();

    // ---- wave -> (row, 4 consecutive groups) ----
    const int row = blockIdx.x >> 2;                       // 4096 blocks / 4
    const int g0  = ((blockIdx.x & 3) * 4 + (tid >> 6)) * GPW;
    const float* __restrict__ xr_row = xr + (size_t)row * W_IN;
    const float* __restrict__ xi_row = xi + (size_t)row * W_IN;
    float* __restrict__ out_row = out + (size_t)row * (W_OUT * 2);

    // Lane's B-frag source chunks: A = s + 8*(2rr+jj) (reaches s+264 > row end
    // for the last group -> MUST clamp, R3 crash), B = A + 32. Clamped chunks
    // feed only zero-weight taps of valid outputs or dropped output columns:
    // valid output p<=16352 consumes x'[p..p+31] (<=16383) with nonzero taps;
    // any position >=16384 maps to taps outside the [0,32) band or to output
    // positions > 16352, which the guarded store drops. Chunks are 8-aligned,
    // W_IN % 8 == 0 -> clamped loads stay 32B-aligned and never split.
    const int lofs = 8 * (2 * rr + jj);
    int pA = g0 * GRP + lofs;

    // ---- prefetch group g0 (8x dwordx4) ----
    float4 pv0, pv1, pv2, pv3, pv4, pv5, pv6, pv7;
    {
        const int a = min(pA, PMAX);
        const int b = min(pA + 32, PMAX);
        pv0 = *(const float4*)(xr_row + a);     pv1 = *(const float4*)(xr_row + a + 4);
        pv2 = *(const float4*)(xr_row + b);     pv3 = *(const float4*)(xr_row + b + 4);
        pv4 = *(const float4*)(xi_row + a);     pv5 = *(const float4*)(xi_row + a + 4);
        pv6 = *(const float4*)(xi_row + b);     pv7 = *(const float4*)(xi_row + b + 4);
    }

#pragma unroll
    for (int gi = 0; gi < GPW; ++gi) {
        const int s = (g0 + gi) * GRP;

        // ---- envelope + MLP -> bf16 hi/lo fragments (consumes pv) ----
        short8 xrh0, xrl0, xih0, xil0, xrh1, xrl1, xih1, xil1;
        env8(slut, pv0, pv1, pv4, pv5, xrh0, xrl0, xih0, xil0);
        env8(slut, pv2, pv3, pv6, pv7, xrh1, xrl1, xih1, xil1);

        // ---- issue next group's loads; they fly under MFMA + stores ----
        if (gi != GPW - 1) {
            const int pA2 = pA + GRP;
            const int a = min(pA2, PMAX);
            const int b = min(pA2 + 32, PMAX);
            pv0 = *(const float4*)(xr_row + a); pv1 = *(const float4*)(xr_row + a + 4);
            pv2 = *(const float4*)(xr_row + b); pv3 = *(const float4*)(xr_row + b + 4);
            pv4 = *(const float4*)(xi_row + a); pv5 = *(const float4*)(xi_row + a + 4);
            pv6 = *(const float4*)(xi_row + b); pv7 = *(const float4*)(xi_row + b + 4);
            pA = pA2;
        }

        // ---- complex FIR via MFMA, 3 chains: yr = acr - acs, yi = aci ----
        f32x4 acr = {0.f, 0.f, 0.f, 0.f};   // fr (x) xr   (hi/lo 3-product)
        f32x4 aci = {0.f, 0.f, 0.f, 0.f};   // fr (x) xi + fi (x) xr
        f32x4 acs = {0.f, 0.f, 0.f, 0.f};   // fi (x) xi
        aci = MFMA(frh[0], xih0, aci); acr = MFMA(frh[0], xrh0, acr); acs = MFMA(fih[0], xih0, acs);
        aci = MFMA(frh[1], xih1, aci); acr = MFMA(frh[1], xrh1, acr); acs = MFMA(fih[1], xih1, acs);
        aci = MFMA(fih[0], xrh0, aci); acr = MFMA(frh[0], xrl0, acr); acs = MFMA(fih[0], xil0, acs);
        aci = MFMA(fih[1], xrh1, aci); acr = MFMA(frh[1], xrl1, acr); acs = MFMA(fih[1], xil1, acs);
        aci = MFMA(frh[0], xil0, aci); acr = MFMA(frl[0], xrh0, acr); acs = MFMA(fil[0], xih0, acs);
        aci = MFMA(frh[1], xil1, aci); acr = MFMA(frl[1], xrh1, acr); acs = MFMA(fil[1], xih1, acs);
        aci = MFMA(frl[0], xih0, aci);
        aci = MFMA(frl[1], xih1, aci);
        aci = MFMA(fil[0], xrh0, aci);
        aci = MFMA(fil[1], xrh1, aci);
        aci = MFMA(fih[0], xrl0, aci);
        aci = MFMA(fih[1], xrl1, aci);

        // ---- store: D col=lane&15, row=4*jj+q -> 4 consecutive outputs ----
        const int p0 = s + 16 * rr + 4 * jj;
        float* dst = out_row + (size_t)p0 * 2;
        if (s + GRP <= W_OUT) {                  // full group (all but last)
            *(float4*)(dst)     = make_float4(acr[0] - acs[0], aci[0],
                                              acr[1] - acs[1], aci[1]);
            *(float4*)(dst + 4) = make_float4(acr[2] - acs[2], aci[2],
                                              acr[3] - acs[3], aci[3]);
        } else {
#pragma unroll
            for (int q = 0; q < 4; ++q)
                if (p0 + q < W_OUT)
                    *(float2*)(dst + 2 * q) = make_float2(acr[q] - acs[q], aci[q]);
        }
    }
}

extern "C" void kernel_launch(void* const* d_in, const int* in_sizes, int n_in,
                              void* d_out, int out_size, void* d_ws, size_t ws_size,
                              hipStream_t stream) {
    const float* xr  = (const float*)d_in[0];
    const float* xi  = (const float*)d_in[1];
    const float* w1  = (const float*)d_in[2];
    const float* w2  = (const float*)d_in[3];
    const float* wlr = (const float*)d_in[4];
    const float* wli = (const float*)d_in[5];
    float* out = (float*)d_out;
    float2* lut2 = (float2*)d_ws;                    // 2048 float2 = 16 KB

    build_lut_kernel<<<dim3(LUT_N / NT), dim3(NT), 0, stream>>>(w1, w2, lut2);

    const int rows = 16 * 64;                        // B*H = 1024
    const int blocks = rows * (NGRP / (4 * GPW));    // 1024 * 4 = 4096
    fused_env_mlp_fir_kernel<<<dim3(blocks), dim3(NT), 0, stream>>>(
        xr, xi, lut2, wlr, wli, out);
}